// Round 1
// baseline (2508.763 us; speedup 1.0000x reference)
//
#include <hip/hip_runtime.h>

typedef _Float16 h2 __attribute__((ext_vector_type(2)));
typedef unsigned int u32;

#define TB 512

// ---- LDS byte offsets ----
// phase 1: X fp32 [3][36][36] @ 0          (15552 B)
//          A h2   [6][34][34] @ 15552      (27744 B)  channel pairs (s, s+1)
//          B h2   [6][34][34] @ 43296      (27744 B)  -> phase-1 end 71040 B
// phase 2: H h2 chunk [14][36][38] @ 0     (76608 B)  d-pairs, overlays all
// max 76608 B  -> 2 blocks/CU (2*76608 = 153216 <= 163840)
#define AOFF 15552
#define BOFF 43296
#define LDS_BYTES 76608

__device__ __forceinline__ u32 packh2(float a, float b) {
    union { h2 h; u32 u; } v;
    v.h.x = (_Float16)a;
    v.h.y = (_Float16)b;
    return v.u;
}
__device__ __forceinline__ h2 as_h2(u32 u) {
    union { u32 u; h2 h; } v; v.u = u; return v.h;
}
__device__ __forceinline__ float fdot2(h2 a, h2 b, float c) {
    // v_dot2_f32_f16: c + a.x*b.x + a.y*b.y, fp32 accumulate
    return __builtin_amdgcn_fdot2(a, b, c, false);
}

// ---------------- weight pre-pack: fp32 -> fp16 channel pairs ----------------
// midp  : [4 layers][c:12][ep:6][ky:3][kx:3] u32  (pair = in-ch 2ep, 2ep+1)   = 2592
// tailp : [dp:28][ky:9][c:3][kx:9] u32          (pair = d 2dp, 2dp+1)          = 6804
__global__ void pack_w(const float* __restrict__ b1_w, const float* __restrict__ b2_w,
                       const float* __restrict__ b3_w, const float* __restrict__ b4_w,
                       const float* __restrict__ tail_w, u32* __restrict__ dst)
{
    const int i = blockIdx.x * blockDim.x + threadIdx.x;
    if (i < 2592) {
        const int L   = i / 648;
        const int rem = i - L * 648;          // (c*6+ep)*9 + ky*3 + kx
        const int c   = rem / 54;
        const int r2  = rem - c * 54;
        const int ep  = r2 / 9;
        const int k   = r2 - ep * 9;          // ky*3+kx
        const float* w = (L == 0) ? b1_w : (L == 1) ? b2_w : (L == 2) ? b3_w : b4_w;
        const float w0 = w[(c * 12 + 2 * ep) * 9 + k];
        const float w1 = w[(c * 12 + 2 * ep + 1) * 9 + k];
        dst[i] = packh2(w0, w1);
    } else if (i < 2592 + 6804) {
        const int t  = i - 2592;              // ((dp*9+ky)*3+c)*9+kx
        const int dp = t / 243;
        const int r2 = t - dp * 243;
        const int ky = r2 / 27;
        const int r3 = r2 - ky * 27;
        const int c  = r3 / 9;
        const int kx = r3 - c * 9;
        const float w0 = tail_w[((2 * dp)     * 3 + c) * 81 + ky * 9 + kx];
        const float w1 = tail_w[((2 * dp + 1) * 3 + c) * 81 + ky * 9 + kx];
        dst[2592 + t] = packh2(w0, w1);
    }
}

__global__ void __launch_bounds__(TB, 4)
fsrcnn_fused(const float* __restrict__ x,
             const float* __restrict__ head_w, const float* __restrict__ head_b, const float* __restrict__ head_a,
             const float* __restrict__ b0_w, const float* __restrict__ b0_b, const float* __restrict__ b0_a,
             const float* __restrict__ b1_b, const float* __restrict__ b2_b,
             const float* __restrict__ b3_b, const float* __restrict__ b4_b,
             const float* __restrict__ b5_a,
             const float* __restrict__ b6_w, const float* __restrict__ b6_b, const float* __restrict__ b6_a,
             const float* __restrict__ tail_b,
             const u32* __restrict__ midp, const u32* __restrict__ tailp,
             float* __restrict__ out)
{
    extern __shared__ char smem[];
    float* const Xf = reinterpret_cast<float*>(smem);           // [3][36][36]
    u32*   const Au = reinterpret_cast<u32*>(smem + AOFF);      // h2 [6][34][34]
    u32*   const Bu = reinterpret_cast<u32*>(smem + BOFF);
    u32*   const Hw = reinterpret_cast<u32*>(smem);             // h2 [14][36][38]

    const int tid = threadIdx.x;
    const int img = blockIdx.x;
    const int y   = tid >> 4;          // 0..31 pixel row
    const int x0  = (tid & 15) << 1;   // 0..30 pixel col base (2 px/thread)

    // ---------------- stage padded x (3x36x36), zero A+B ----------------
    {
        const float* xg = x + img * 3072;
        for (int i = tid; i < 3888; i += TB) {
            const int c = i / 1296;
            const int rem = i - c * 1296;
            const int r = rem / 36;
            const int cl = rem - r * 36;
            const int iy = r - 2, ix = cl - 2;
            float v = 0.f;
            if ((unsigned)iy < 32u && (unsigned)ix < 32u)
                v = xg[(c << 10) + (iy << 5) + ix];
            Xf[i] = v;
        }
        float4* ab = reinterpret_cast<float4*>(smem + AOFF);
        const float4 z4 = make_float4(0.f, 0.f, 0.f, 0.f);
        for (int i = tid; i < 3468; i += TB) ab[i] = z4;   // zero A and B (55488 B)
    }
    __syncthreads();

    // ---------------- head 5x5 3->56 + prelu + b0 1x1 56->12 + prelu -> A (h2 pairs) ----------------
    float accS[12][2];
    #pragma unroll
    for (int s = 0; s < 12; s++) { const float bb = b0_b[s]; accS[s][0] = bb; accS[s][1] = bb; }
    for (int d0 = 0; d0 < 56; d0 += 4) {
        float ah[4][2];
        #pragma unroll
        for (int dd = 0; dd < 4; dd++) { const float hb = head_b[d0 + dd]; ah[dd][0] = hb; ah[dd][1] = hb; }
        #pragma unroll
        for (int ci = 0; ci < 3; ci++) {
            #pragma unroll
            for (int ky = 0; ky < 5; ky++) {
                const float* xr = &Xf[ci * 1296 + (y + ky) * 36 + x0];
                float xv[6];
                *reinterpret_cast<float2*>(&xv[0]) = *reinterpret_cast<const float2*>(xr);
                *reinterpret_cast<float2*>(&xv[2]) = *reinterpret_cast<const float2*>(xr + 2);
                *reinterpret_cast<float2*>(&xv[4]) = *reinterpret_cast<const float2*>(xr + 4);
                #pragma unroll
                for (int dd = 0; dd < 4; dd++) {
                    const float* wr = &head_w[((d0 + dd) * 3 + ci) * 25 + ky * 5];
                    #pragma unroll
                    for (int kx = 0; kx < 5; kx++) {
                        const float w = wr[kx];                       // uniform -> s_load
                        ah[dd][0] = fmaf(xv[kx],     w, ah[dd][0]);
                        ah[dd][1] = fmaf(xv[kx + 1], w, ah[dd][1]);
                    }
                }
            }
        }
        #pragma unroll
        for (int dd = 0; dd < 4; dd++) {
            const float al = head_a[d0 + dd];
            float v0 = ah[dd][0]; v0 = (v0 >= 0.f) ? v0 : al * v0;
            float v1 = ah[dd][1]; v1 = (v1 >= 0.f) ? v1 : al * v1;
            #pragma unroll
            for (int s = 0; s < 12; s++) {
                const float w = b0_w[s * 56 + d0 + dd];               // uniform -> s_load
                accS[s][0] = fmaf(w, v0, accS[s][0]);
                accS[s][1] = fmaf(w, v1, accS[s][1]);
            }
        }
    }
    #pragma unroll
    for (int sp = 0; sp < 6; sp++) {
        const float a0 = b0_a[2 * sp], a1 = b0_a[2 * sp + 1];
        float u0 = accS[2 * sp][0];     u0 = (u0 >= 0.f) ? u0 : a0 * u0;
        float u1 = accS[2 * sp][1];     u1 = (u1 >= 0.f) ? u1 : a0 * u1;
        float v0 = accS[2 * sp + 1][0]; v0 = (v0 >= 0.f) ? v0 : a1 * v0;
        float v1 = accS[2 * sp + 1][1]; v1 = (v1 >= 0.f) ? v1 : a1 * v1;
        const int o = sp * 1156 + (y + 1) * 34 + x0 + 1;
        Au[o]     = packh2(u0, v0);
        Au[o + 1] = packh2(u1, v1);
    }
    __syncthreads();

    // ---------------- b1..b3: 3x3 12->12 pad1, h2 dot2, LDS->LDS ----------------
    auto conv3h = [&](const u32* __restrict__ P, u32* __restrict__ Q,
                      const u32* __restrict__ wp, const float* __restrict__ bias) {
        float acc[12][2];
        #pragma unroll
        for (int c = 0; c < 12; c++) { const float bb = bias[c]; acc[c][0] = bb; acc[c][1] = bb; }
        for (int ep = 0; ep < 6; ep++) {
            #pragma unroll
            for (int ky = 0; ky < 3; ky++) {
                const int idx = ep * 1156 + (y + ky) * 34 + x0;
                const uint2 q0 = *reinterpret_cast<const uint2*>(&P[idx]);
                const uint2 q1 = *reinterpret_cast<const uint2*>(&P[idx + 2]);
                h2 xh[4] = { as_h2(q0.x), as_h2(q0.y), as_h2(q1.x), as_h2(q1.y) };
                const u32* wr = wp + ep * 9 + ky * 3;
                #pragma unroll
                for (int c = 0; c < 12; c++) {
                    #pragma unroll
                    for (int kx = 0; kx < 3; kx++) {
                        const h2 wv = as_h2(wr[c * 54 + kx]);          // uniform -> s_load
                        acc[c][0] = fdot2(xh[kx],     wv, acc[c][0]);
                        acc[c][1] = fdot2(xh[kx + 1], wv, acc[c][1]);
                    }
                }
            }
        }
        #pragma unroll
        for (int cp = 0; cp < 6; cp++) {
            const int o = cp * 1156 + (y + 1) * 34 + x0 + 1;
            Q[o]     = packh2(acc[2 * cp][0], acc[2 * cp + 1][0]);
            Q[o + 1] = packh2(acc[2 * cp][1], acc[2 * cp + 1][1]);
        }
        __syncthreads();
    };
    conv3h(Au, Bu, midp +    0, b1_b);
    conv3h(Bu, Au, midp +  648, b2_b);
    conv3h(Au, Bu, midp + 1296, b3_b);

    // ---------------- b4: 3x3 dot2 + prelu(b5_a) -> registers g ----------------
    float g[12][2];
    #pragma unroll
    for (int c = 0; c < 12; c++) { const float bb = b4_b[c]; g[c][0] = bb; g[c][1] = bb; }
    {
        const u32* wp = midp + 1944;
        for (int ep = 0; ep < 6; ep++) {
            #pragma unroll
            for (int ky = 0; ky < 3; ky++) {
                const int idx = ep * 1156 + (y + ky) * 34 + x0;
                const uint2 q0 = *reinterpret_cast<const uint2*>(&Bu[idx]);
                const uint2 q1 = *reinterpret_cast<const uint2*>(&Bu[idx + 2]);
                h2 xh[4] = { as_h2(q0.x), as_h2(q0.y), as_h2(q1.x), as_h2(q1.y) };
                const u32* wr = wp + ep * 9 + ky * 3;
                #pragma unroll
                for (int c = 0; c < 12; c++) {
                    #pragma unroll
                    for (int kx = 0; kx < 3; kx++) {
                        const h2 wv = as_h2(wr[c * 54 + kx]);
                        g[c][0] = fdot2(xh[kx],     wv, g[c][0]);
                        g[c][1] = fdot2(xh[kx + 1], wv, g[c][1]);
                    }
                }
            }
        }
    }
    #pragma unroll
    for (int c = 0; c < 12; c++) {
        const float al = b5_a[c];
        float v0 = g[c][0]; g[c][0] = (v0 >= 0.f) ? v0 : al * v0;
        float v1 = g[c][1]; g[c][1] = (v1 >= 0.f) ? v1 : al * v1;
    }
    __syncthreads();   // last reads of B done -> safe to overlay H

    // ---------------- b6 1x1 + prelu -> H (d-paired, 2 chunks of 28 ch) + tail ----------------
    float accT[2][3][4];
    {
        const float tb0 = tail_b[0], tb1 = tail_b[1], tb2 = tail_b[2];
        #pragma unroll
        for (int q = 0; q < 4; q++) {
            accT[0][0][q] = tb0; accT[0][1][q] = tb1; accT[0][2][q] = tb2;
            accT[1][0][q] = tb0; accT[1][1][q] = tb1; accT[1][2][q] = tb2;
        }
    }

    for (int ck = 0; ck < 2; ck++) {
        // b6 for this chunk's 14 d-pairs
        for (int dpl = 0; dpl < 14; dpl++) {
            const int d = (ck * 14 + dpl) * 2;
            float va0 = b6_b[d],     va1 = va0;
            float vb0 = b6_b[d + 1], vb1 = vb0;
            #pragma unroll
            for (int s = 0; s < 12; s++) {
                const float wa = b6_w[d * 12 + s];                    // uniform -> s_load
                const float wb = b6_w[(d + 1) * 12 + s];
                va0 = fmaf(wa, g[s][0], va0); va1 = fmaf(wa, g[s][1], va1);
                vb0 = fmaf(wb, g[s][0], vb0); vb1 = fmaf(wb, g[s][1], vb1);
            }
            const float aa = b6_a[d], ab = b6_a[d + 1];
            va0 = (va0 >= 0.f) ? va0 : aa * va0;
            va1 = (va1 >= 0.f) ? va1 : aa * va1;
            vb0 = (vb0 >= 0.f) ? vb0 : ab * vb0;
            vb1 = (vb1 >= 0.f) ? vb1 : ab * vb1;
            const int o = dpl * 1368 + (y + 2) * 38 + x0 + 2;
            Hw[o]     = packh2(va0, vb0);
            Hw[o + 1] = packh2(va1, vb1);
        }
        if (ck == 0) {
            // zero frame once (chunk 1 reuses it: interior writes never touch frame)
            const uint2 z2 = make_uint2(0u, 0u);
            for (int i = tid; i < 1008; i += TB) {      // rows 0,1,34,35 x cols 0..35
                const int dp = i / 72;
                const int rem = i - dp * 72;
                const int rr = rem / 18;
                const int cc = (rem - rr * 18) * 2;
                const int row = (rr & 1) + (rr >> 1) * 34;
                *reinterpret_cast<uint2*>(&Hw[dp * 1368 + row * 38 + cc]) = z2;
            }
            for (int i = tid; i < 896; i += TB) {       // cols 0,1 / 34,35, rows 2..33
                const int dp = i >> 6;
                const int rem = i & 63;
                const int row = 2 + (rem >> 1);
                const int col = (rem & 1) * 34;
                *reinterpret_cast<uint2*>(&Hw[dp * 1368 + row * 38 + col]) = z2;
            }
        }
        __syncthreads();

        // tail: 9x9 stride-2 convT, dot2 over d-pairs; H rows shared by both ry
        const u32* tw = tailp + ck * 3402;   // 14*243
        #pragma unroll
        for (int m = 0; m < 5; m++) {
            const int r = y + 4 - m;                    // padded row, in [0,35]
            for (int dpl = 0; dpl < 14; dpl++) {
                const int base = dpl * 1368 + r * 38 + x0;
                const uint2 q0 = *reinterpret_cast<const uint2*>(&Hw[base]);
                const uint2 q1 = *reinterpret_cast<const uint2*>(&Hw[base + 2]);
                const uint2 q2 = *reinterpret_cast<const uint2*>(&Hw[base + 4]);
                h2 xh[6] = { as_h2(q0.x), as_h2(q0.y), as_h2(q1.x),
                             as_h2(q1.y), as_h2(q2.x), as_h2(q2.y) };
                const u32* w0 = tw + dpl * 243 + (2 * m) * 27;   // ky = 2m   (ry=0)
                #pragma unroll
                for (int kx = 0; kx < 9; kx++) {
                    const int n = kx >> 1, rx = kx & 1;
                    #pragma unroll
                    for (int c = 0; c < 3; c++) {
                        const h2 wv = as_h2(w0[c * 9 + kx]);     // uniform -> s_load
                        accT[0][c][rx]     = fdot2(xh[4 - n], wv, accT[0][c][rx]);
                        accT[0][c][2 + rx] = fdot2(xh[5 - n], wv, accT[0][c][2 + rx]);
                    }
                }
                if (m < 4) {
                    const u32* w1 = w0 + 27;                     // ky = 2m+1 (ry=1)
                    #pragma unroll
                    for (int kx = 0; kx < 9; kx++) {
                        const int n = kx >> 1, rx = kx & 1;
                        #pragma unroll
                        for (int c = 0; c < 3; c++) {
                            const h2 wv = as_h2(w1[c * 9 + kx]);
                            accT[1][c][rx]     = fdot2(xh[4 - n], wv, accT[1][c][rx]);
                            accT[1][c][2 + rx] = fdot2(xh[5 - n], wv, accT[1][c][2 + rx]);
                        }
                    }
                }
            }
        }
        if (ck == 0) __syncthreads();   // chunk-0 reads done before chunk-1 overwrites H
    }

    // ---------------- store ----------------
    #pragma unroll
    for (int ry = 0; ry < 2; ry++) {
        const int oy = 2 * y + ry;
        float* op = out + (img * 3) * 4096 + oy * 64 + (x0 << 1);
        #pragma unroll
        for (int c = 0; c < 3; c++)
            *reinterpret_cast<float4*>(op + c * 4096) =
                make_float4(accT[ry][c][0], accT[ry][c][1], accT[ry][c][2], accT[ry][c][3]);
    }
}

extern "C" void kernel_launch(void* const* d_in, const int* in_sizes, int n_in,
                              void* d_out, int out_size, void* d_ws, size_t ws_size,
                              hipStream_t stream) {
    (void)in_sizes; (void)n_in; (void)ws_size; (void)out_size;
    const float* x      = (const float*)d_in[0];
    const float* head_w = (const float*)d_in[1];
    const float* head_b = (const float*)d_in[2];
    const float* head_a = (const float*)d_in[3];
    const float* b0_w   = (const float*)d_in[4];
    const float* b0_b   = (const float*)d_in[5];
    const float* b0_a   = (const float*)d_in[6];
    const float* b1_w   = (const float*)d_in[7];
    const float* b1_b   = (const float*)d_in[8];
    const float* b2_w   = (const float*)d_in[9];
    const float* b2_b   = (const float*)d_in[10];
    const float* b3_w   = (const float*)d_in[11];
    const float* b3_b   = (const float*)d_in[12];
    const float* b4_w   = (const float*)d_in[13];
    const float* b4_b   = (const float*)d_in[14];
    const float* b5_a   = (const float*)d_in[15];
    const float* b6_w   = (const float*)d_in[16];
    const float* b6_b   = (const float*)d_in[17];
    const float* b6_a   = (const float*)d_in[18];
    const float* tail_w = (const float*)d_in[19];
    const float* tail_b = (const float*)d_in[20];
    float* out = (float*)d_out;

    u32* wpk = (u32*)d_ws;            // 2592 mid + 6804 tail = 9396 u32 = 37584 B
    pack_w<<<37, 256, 0, stream>>>(b1_w, b2_w, b3_w, b4_w, tail_w, wpk);

    hipFuncSetAttribute(reinterpret_cast<const void*>(fsrcnn_fused),
                        hipFuncAttributeMaxDynamicSharedMemorySize, LDS_BYTES);
    fsrcnn_fused<<<1024, TB, LDS_BYTES, stream>>>(
        x, head_w, head_b, head_a, b0_w, b0_b, b0_a,
        b1_b, b2_b, b3_b, b4_b, b5_a,
        b6_w, b6_b, b6_a, tail_b,
        wpk, wpk + 2592, out);
}

// Round 2
// 752.873 us; speedup vs baseline: 3.3323x; 3.3323x over previous
//
#include <hip/hip_runtime.h>

typedef _Float16 h2 __attribute__((ext_vector_type(2)));
typedef unsigned int u32;

#define TB 512

// ---- LDS byte offsets ----
// phase 1: X fp32 [3][36][36] @ 0          (15552 B)
//          A h2   [6][34][34] @ 15552      (27744 B)  channel pairs (s, s+1)
//          B h2   [6][34][34] @ 43296      (27744 B)  -> phase-1 end 71040 B
// phase 2: H h2 chunk [14][36][38] @ 0     (76608 B)  d-pairs, overlays all
// max 76608 B  -> 2 blocks/CU (2*76608 = 153216 <= 163840)
#define AOFF 15552
#define BOFF 43296
#define LDS_BYTES 76608

__device__ __forceinline__ u32 packh2(float a, float b) {
    union { h2 h; u32 u; } v;
    v.h.x = (_Float16)a;
    v.h.y = (_Float16)b;
    return v.u;
}
__device__ __forceinline__ h2 as_h2(u32 u) {
    union { u32 u; h2 h; } v; v.u = u; return v.h;
}
__device__ __forceinline__ float fdot2(h2 a, h2 b, float c) {
    // v_dot2_f32_f16: c + a.x*b.x + a.y*b.y, fp32 accumulate
    return __builtin_amdgcn_fdot2(a, b, c, false);
}

// ---------------- weight pre-pack: fp32 -> fp16 channel pairs ----------------
// midp  : [4 layers][c:12][ep:6][ky:3][kx:3] u32  (pair = in-ch 2ep, 2ep+1)   = 2592
// tailp : [dp:28][ky:9][c:3][kx:9] u32          (pair = d 2dp, 2dp+1)          = 6804
__global__ void pack_w(const float* __restrict__ b1_w, const float* __restrict__ b2_w,
                       const float* __restrict__ b3_w, const float* __restrict__ b4_w,
                       const float* __restrict__ tail_w, u32* __restrict__ dst)
{
    const int i = blockIdx.x * blockDim.x + threadIdx.x;
    if (i < 2592) {
        const int L   = i / 648;
        const int rem = i - L * 648;          // (c*6+ep)*9 + ky*3 + kx
        const int c   = rem / 54;
        const int r2  = rem - c * 54;
        const int ep  = r2 / 9;
        const int k   = r2 - ep * 9;          // ky*3+kx
        const float* w = (L == 0) ? b1_w : (L == 1) ? b2_w : (L == 2) ? b3_w : b4_w;
        const float w0 = w[(c * 12 + 2 * ep) * 9 + k];
        const float w1 = w[(c * 12 + 2 * ep + 1) * 9 + k];
        dst[i] = packh2(w0, w1);
    } else if (i < 2592 + 6804) {
        const int t  = i - 2592;              // ((dp*9+ky)*3+c)*9+kx
        const int dp = t / 243;
        const int r2 = t - dp * 243;
        const int ky = r2 / 27;
        const int r3 = r2 - ky * 27;
        const int c  = r3 / 9;
        const int kx = r3 - c * 9;
        const float w0 = tail_w[((2 * dp)     * 3 + c) * 81 + ky * 9 + kx];
        const float w1 = tail_w[((2 * dp + 1) * 3 + c) * 81 + ky * 9 + kx];
        dst[2592 + t] = packh2(w0, w1);
    }
}

// NOTE on launch bounds: on this toolchain the 2nd arg empirically acts as
// workgroups/CU for 512-thread blocks: (512,2) -> VGPR cap 128 (round 0),
// (512,4) -> VGPR cap 64 which SPILLED accumulators to scratch (round 1:
// 7.4 GB HBM traffic, 2.6x regression). We need exactly 128 VGPRs:
// 4 waves/SIMD * 128 = 512-reg file, and 2 blocks/CU is the LDS-driven goal.
__global__ void __launch_bounds__(TB, 2)
fsrcnn_fused(const float* __restrict__ x,
             const float* __restrict__ head_w, const float* __restrict__ head_b, const float* __restrict__ head_a,
             const float* __restrict__ b0_w, const float* __restrict__ b0_b, const float* __restrict__ b0_a,
             const float* __restrict__ b1_b, const float* __restrict__ b2_b,
             const float* __restrict__ b3_b, const float* __restrict__ b4_b,
             const float* __restrict__ b5_a,
             const float* __restrict__ b6_w, const float* __restrict__ b6_b, const float* __restrict__ b6_a,
             const float* __restrict__ tail_b,
             const u32* __restrict__ midp, const u32* __restrict__ tailp,
             float* __restrict__ out)
{
    extern __shared__ char smem[];
    float* const Xf = reinterpret_cast<float*>(smem);           // [3][36][36]
    u32*   const Au = reinterpret_cast<u32*>(smem + AOFF);      // h2 [6][34][34]
    u32*   const Bu = reinterpret_cast<u32*>(smem + BOFF);
    u32*   const Hw = reinterpret_cast<u32*>(smem);             // h2 [14][36][38]

    const int tid = threadIdx.x;
    const int img = blockIdx.x;
    const int y   = tid >> 4;          // 0..31 pixel row
    const int x0  = (tid & 15) << 1;   // 0..30 pixel col base (2 px/thread)

    // ---------------- stage padded x (3x36x36), zero A+B ----------------
    {
        const float* xg = x + img * 3072;
        for (int i = tid; i < 3888; i += TB) {
            const int c = i / 1296;
            const int rem = i - c * 1296;
            const int r = rem / 36;
            const int cl = rem - r * 36;
            const int iy = r - 2, ix = cl - 2;
            float v = 0.f;
            if ((unsigned)iy < 32u && (unsigned)ix < 32u)
                v = xg[(c << 10) + (iy << 5) + ix];
            Xf[i] = v;
        }
        float4* ab = reinterpret_cast<float4*>(smem + AOFF);
        const float4 z4 = make_float4(0.f, 0.f, 0.f, 0.f);
        for (int i = tid; i < 3468; i += TB) ab[i] = z4;   // zero A and B (55488 B)
    }
    __syncthreads();

    // ---------------- head 5x5 3->56 + prelu + b0 1x1 56->12 + prelu -> A (h2 pairs) ----------------
    float accS[12][2];
    #pragma unroll
    for (int s = 0; s < 12; s++) { const float bb = b0_b[s]; accS[s][0] = bb; accS[s][1] = bb; }
    for (int d0 = 0; d0 < 56; d0 += 4) {
        float ah[4][2];
        #pragma unroll
        for (int dd = 0; dd < 4; dd++) { const float hb = head_b[d0 + dd]; ah[dd][0] = hb; ah[dd][1] = hb; }
        #pragma unroll
        for (int ci = 0; ci < 3; ci++) {
            #pragma unroll
            for (int ky = 0; ky < 5; ky++) {
                const float* xr = &Xf[ci * 1296 + (y + ky) * 36 + x0];
                float xv[6];
                *reinterpret_cast<float2*>(&xv[0]) = *reinterpret_cast<const float2*>(xr);
                *reinterpret_cast<float2*>(&xv[2]) = *reinterpret_cast<const float2*>(xr + 2);
                *reinterpret_cast<float2*>(&xv[4]) = *reinterpret_cast<const float2*>(xr + 4);
                #pragma unroll
                for (int dd = 0; dd < 4; dd++) {
                    const float* wr = &head_w[((d0 + dd) * 3 + ci) * 25 + ky * 5];
                    #pragma unroll
                    for (int kx = 0; kx < 5; kx++) {
                        const float w = wr[kx];                       // uniform -> s_load
                        ah[dd][0] = fmaf(xv[kx],     w, ah[dd][0]);
                        ah[dd][1] = fmaf(xv[kx + 1], w, ah[dd][1]);
                    }
                }
            }
        }
        #pragma unroll
        for (int dd = 0; dd < 4; dd++) {
            const float al = head_a[d0 + dd];
            float v0 = ah[dd][0]; v0 = (v0 >= 0.f) ? v0 : al * v0;
            float v1 = ah[dd][1]; v1 = (v1 >= 0.f) ? v1 : al * v1;
            #pragma unroll
            for (int s = 0; s < 12; s++) {
                const float w = b0_w[s * 56 + d0 + dd];               // uniform -> s_load
                accS[s][0] = fmaf(w, v0, accS[s][0]);
                accS[s][1] = fmaf(w, v1, accS[s][1]);
            }
        }
    }
    #pragma unroll
    for (int sp = 0; sp < 6; sp++) {
        const float a0 = b0_a[2 * sp], a1 = b0_a[2 * sp + 1];
        float u0 = accS[2 * sp][0];     u0 = (u0 >= 0.f) ? u0 : a0 * u0;
        float u1 = accS[2 * sp][1];     u1 = (u1 >= 0.f) ? u1 : a0 * u1;
        float v0 = accS[2 * sp + 1][0]; v0 = (v0 >= 0.f) ? v0 : a1 * v0;
        float v1 = accS[2 * sp + 1][1]; v1 = (v1 >= 0.f) ? v1 : a1 * v1;
        const int o = sp * 1156 + (y + 1) * 34 + x0 + 1;
        Au[o]     = packh2(u0, v0);
        Au[o + 1] = packh2(u1, v1);
    }
    __syncthreads();

    // ---------------- b1..b3: 3x3 12->12 pad1, h2 dot2, LDS->LDS ----------------
    auto conv3h = [&](const u32* __restrict__ P, u32* __restrict__ Q,
                      const u32* __restrict__ wp, const float* __restrict__ bias) {
        float acc[12][2];
        #pragma unroll
        for (int c = 0; c < 12; c++) { const float bb = bias[c]; acc[c][0] = bb; acc[c][1] = bb; }
        for (int ep = 0; ep < 6; ep++) {
            #pragma unroll
            for (int ky = 0; ky < 3; ky++) {
                const int idx = ep * 1156 + (y + ky) * 34 + x0;
                const uint2 q0 = *reinterpret_cast<const uint2*>(&P[idx]);
                const uint2 q1 = *reinterpret_cast<const uint2*>(&P[idx + 2]);
                h2 xh[4] = { as_h2(q0.x), as_h2(q0.y), as_h2(q1.x), as_h2(q1.y) };
                const u32* wr = wp + ep * 9 + ky * 3;
                #pragma unroll
                for (int c = 0; c < 12; c++) {
                    #pragma unroll
                    for (int kx = 0; kx < 3; kx++) {
                        const h2 wv = as_h2(wr[c * 54 + kx]);          // uniform -> s_load
                        acc[c][0] = fdot2(xh[kx],     wv, acc[c][0]);
                        acc[c][1] = fdot2(xh[kx + 1], wv, acc[c][1]);
                    }
                }
            }
        }
        #pragma unroll
        for (int cp = 0; cp < 6; cp++) {
            const int o = cp * 1156 + (y + 1) * 34 + x0 + 1;
            Q[o]     = packh2(acc[2 * cp][0], acc[2 * cp + 1][0]);
            Q[o + 1] = packh2(acc[2 * cp][1], acc[2 * cp + 1][1]);
        }
        __syncthreads();
    };
    conv3h(Au, Bu, midp +    0, b1_b);
    conv3h(Bu, Au, midp +  648, b2_b);
    conv3h(Au, Bu, midp + 1296, b3_b);

    // ---------------- b4: 3x3 dot2 + prelu(b5_a) -> registers g ----------------
    float g[12][2];
    #pragma unroll
    for (int c = 0; c < 12; c++) { const float bb = b4_b[c]; g[c][0] = bb; g[c][1] = bb; }
    {
        const u32* wp = midp + 1944;
        for (int ep = 0; ep < 6; ep++) {
            #pragma unroll
            for (int ky = 0; ky < 3; ky++) {
                const int idx = ep * 1156 + (y + ky) * 34 + x0;
                const uint2 q0 = *reinterpret_cast<const uint2*>(&Bu[idx]);
                const uint2 q1 = *reinterpret_cast<const uint2*>(&Bu[idx + 2]);
                h2 xh[4] = { as_h2(q0.x), as_h2(q0.y), as_h2(q1.x), as_h2(q1.y) };
                const u32* wr = wp + ep * 9 + ky * 3;
                #pragma unroll
                for (int c = 0; c < 12; c++) {
                    #pragma unroll
                    for (int kx = 0; kx < 3; kx++) {
                        const h2 wv = as_h2(wr[c * 54 + kx]);
                        g[c][0] = fdot2(xh[kx],     wv, g[c][0]);
                        g[c][1] = fdot2(xh[kx + 1], wv, g[c][1]);
                    }
                }
            }
        }
    }
    #pragma unroll
    for (int c = 0; c < 12; c++) {
        const float al = b5_a[c];
        float v0 = g[c][0]; g[c][0] = (v0 >= 0.f) ? v0 : al * v0;
        float v1 = g[c][1]; g[c][1] = (v1 >= 0.f) ? v1 : al * v1;
    }
    __syncthreads();   // last reads of B done -> safe to overlay H

    // ---------------- b6 1x1 + prelu -> H (d-paired, 2 chunks of 28 ch) + tail ----------------
    float accT[2][3][4];
    {
        const float tb0 = tail_b[0], tb1 = tail_b[1], tb2 = tail_b[2];
        #pragma unroll
        for (int q = 0; q < 4; q++) {
            accT[0][0][q] = tb0; accT[0][1][q] = tb1; accT[0][2][q] = tb2;
            accT[1][0][q] = tb0; accT[1][1][q] = tb1; accT[1][2][q] = tb2;
        }
    }

    for (int ck = 0; ck < 2; ck++) {
        // b6 for this chunk's 14 d-pairs
        for (int dpl = 0; dpl < 14; dpl++) {
            const int d = (ck * 14 + dpl) * 2;
            float va0 = b6_b[d],     va1 = va0;
            float vb0 = b6_b[d + 1], vb1 = vb0;
            #pragma unroll
            for (int s = 0; s < 12; s++) {
                const float wa = b6_w[d * 12 + s];                    // uniform -> s_load
                const float wb = b6_w[(d + 1) * 12 + s];
                va0 = fmaf(wa, g[s][0], va0); va1 = fmaf(wa, g[s][1], va1);
                vb0 = fmaf(wb, g[s][0], vb0); vb1 = fmaf(wb, g[s][1], vb1);
            }
            const float aa = b6_a[d], ab = b6_a[d + 1];
            va0 = (va0 >= 0.f) ? va0 : aa * va0;
            va1 = (va1 >= 0.f) ? va1 : aa * va1;
            vb0 = (vb0 >= 0.f) ? vb0 : ab * vb0;
            vb1 = (vb1 >= 0.f) ? vb1 : ab * vb1;
            const int o = dpl * 1368 + (y + 2) * 38 + x0 + 2;
            Hw[o]     = packh2(va0, vb0);
            Hw[o + 1] = packh2(va1, vb1);
        }
        if (ck == 0) {
            // zero frame once (chunk 1 reuses it: interior writes never touch frame)
            const uint2 z2 = make_uint2(0u, 0u);
            for (int i = tid; i < 1008; i += TB) {      // rows 0,1,34,35 x cols 0..35
                const int dp = i / 72;
                const int rem = i - dp * 72;
                const int rr = rem / 18;
                const int cc = (rem - rr * 18) * 2;
                const int row = (rr & 1) + (rr >> 1) * 34;
                *reinterpret_cast<uint2*>(&Hw[dp * 1368 + row * 38 + cc]) = z2;
            }
            for (int i = tid; i < 896; i += TB) {       // cols 0,1 / 34,35, rows 2..33
                const int dp = i >> 6;
                const int rem = i & 63;
                const int row = 2 + (rem >> 1);
                const int col = (rem & 1) * 34;
                *reinterpret_cast<uint2*>(&Hw[dp * 1368 + row * 38 + col]) = z2;
            }
        }
        __syncthreads();

        // tail: 9x9 stride-2 convT, dot2 over d-pairs; H rows shared by both ry
        const u32* tw = tailp + ck * 3402;   // 14*243
        #pragma unroll
        for (int m = 0; m < 5; m++) {
            const int r = y + 4 - m;                    // padded row, in [0,35]
            for (int dpl = 0; dpl < 14; dpl++) {
                const int base = dpl * 1368 + r * 38 + x0;
                const uint2 q0 = *reinterpret_cast<const uint2*>(&Hw[base]);
                const uint2 q1 = *reinterpret_cast<const uint2*>(&Hw[base + 2]);
                const uint2 q2 = *reinterpret_cast<const uint2*>(&Hw[base + 4]);
                h2 xh[6] = { as_h2(q0.x), as_h2(q0.y), as_h2(q1.x),
                             as_h2(q1.y), as_h2(q2.x), as_h2(q2.y) };
                const u32* w0 = tw + dpl * 243 + (2 * m) * 27;   // ky = 2m   (ry=0)
                #pragma unroll
                for (int kx = 0; kx < 9; kx++) {
                    const int n = kx >> 1, rx = kx & 1;
                    #pragma unroll
                    for (int c = 0; c < 3; c++) {
                        const h2 wv = as_h2(w0[c * 9 + kx]);     // uniform -> s_load
                        accT[0][c][rx]     = fdot2(xh[4 - n], wv, accT[0][c][rx]);
                        accT[0][c][2 + rx] = fdot2(xh[5 - n], wv, accT[0][c][2 + rx]);
                    }
                }
                if (m < 4) {
                    const u32* w1 = w0 + 27;                     // ky = 2m+1 (ry=1)
                    #pragma unroll
                    for (int kx = 0; kx < 9; kx++) {
                        const int n = kx >> 1, rx = kx & 1;
                        #pragma unroll
                        for (int c = 0; c < 3; c++) {
                            const h2 wv = as_h2(w1[c * 9 + kx]);
                            accT[1][c][rx]     = fdot2(xh[4 - n], wv, accT[1][c][rx]);
                            accT[1][c][2 + rx] = fdot2(xh[5 - n], wv, accT[1][c][2 + rx]);
                        }
                    }
                }
            }
        }
        if (ck == 0) __syncthreads();   // chunk-0 reads done before chunk-1 overwrites H
    }

    // ---------------- store ----------------
    #pragma unroll
    for (int ry = 0; ry < 2; ry++) {
        const int oy = 2 * y + ry;
        float* op = out + (img * 3) * 4096 + oy * 64 + (x0 << 1);
        #pragma unroll
        for (int c = 0; c < 3; c++)
            *reinterpret_cast<float4*>(op + c * 4096) =
                make_float4(accT[ry][c][0], accT[ry][c][1], accT[ry][c][2], accT[ry][c][3]);
    }
}

extern "C" void kernel_launch(void* const* d_in, const int* in_sizes, int n_in,
                              void* d_out, int out_size, void* d_ws, size_t ws_size,
                              hipStream_t stream) {
    (void)in_sizes; (void)n_in; (void)ws_size; (void)out_size;
    const float* x      = (const float*)d_in[0];
    const float* head_w = (const float*)d_in[1];
    const float* head_b = (const float*)d_in[2];
    const float* head_a = (const float*)d_in[3];
    const float* b0_w   = (const float*)d_in[4];
    const float* b0_b   = (const float*)d_in[5];
    const float* b0_a   = (const float*)d_in[6];
    const float* b1_w   = (const float*)d_in[7];
    const float* b1_b   = (const float*)d_in[8];
    const float* b2_w   = (const float*)d_in[9];
    const float* b2_b   = (const float*)d_in[10];
    const float* b3_w   = (const float*)d_in[11];
    const float* b3_b   = (const float*)d_in[12];
    const float* b4_w   = (const float*)d_in[13];
    const float* b4_b   = (const float*)d_in[14];
    const float* b5_a   = (const float*)d_in[15];
    const float* b6_w   = (const float*)d_in[16];
    const float* b6_b   = (const float*)d_in[17];
    const float* b6_a   = (const float*)d_in[18];
    const float* tail_w = (const float*)d_in[19];
    const float* tail_b = (const float*)d_in[20];
    float* out = (float*)d_out;

    u32* wpk = (u32*)d_ws;            // 2592 mid + 6804 tail = 9396 u32 = 37584 B
    pack_w<<<37, 256, 0, stream>>>(b1_w, b2_w, b3_w, b4_w, tail_w, wpk);

    hipFuncSetAttribute(reinterpret_cast<const void*>(fsrcnn_fused),
                        hipFuncAttributeMaxDynamicSharedMemorySize, LDS_BYTES);
    fsrcnn_fused<<<1024, TB, LDS_BYTES, stream>>>(
        x, head_w, head_b, head_a, b0_w, b0_b, b0_a,
        b1_b, b2_b, b3_b, b4_b, b5_a,
        b6_w, b6_b, b6_a, tail_b,
        wpk, wpk + 2592, out);
}